// Round 6
// baseline (92.919 us; speedup 1.0000x reference)
//
#include <hip/hip_runtime.h>
#include <math.h>

// Chamfer one-sided NN distance sum. N = M = 16384, D = 3, fp32 -> scalar fp32.
//
// Two kernels (coop fusion regressed in R4: grid.sync ABI call spilled the
// register arrays; atomics-based single-kernel variants model out neutral).
//
// k1 pair:   grid (ATILES=4, SLICES=256) = 1024 blocks -> 4 blocks/CU,
//            16 waves/CU (R5 ran 2 blocks/CU; suspect latency-bound on the
//            ds_read->fma chain). Each thread owns 16 a-points as 8 v2f;
//            __builtin_elementwise_fma -> v_pk_fma_f32; j-loop unrolled x2
//            with fminf(fminf(t0,t1),best) -> v_min3_f32.
//            2.0 VALU inst/pair (no v_pk_min_f32 on gfx950 — this is the
//            non-MFMA floor). Block stages 64 b-points as
//            float4(-2bx,-2by,-2bz,|b|^2) in LDS (1 KB); unroll-4 batches
//            8 ds_read_b128 per waitcnt for prefetch-ahead scheduling.
//            Partial mins -> ws[slice][a], no atomics. Block (0,0) zeroes
//            out[0] (stream-ordered before k2's atomicAdd).
// k2 reduce: min over 256 slices (coalesced), d = sqrt(max(min+|a|^2,0)),
//            wave + block sum, one atomicAdd per block.

#define BLOCK 256
#define HPT   8                   // <2 x float> per thread -> 16 a-points
#define APT   (2 * HPT)
#define SLICES 256
#define SLICE_LEN 64              // 16384 / SLICES
#define ATILES 4                  // 16384 / (BLOCK * APT)

typedef float v2f __attribute__((ext_vector_type(2)));

__global__ __launch_bounds__(BLOCK)
void cd_pair_kernel(const float* __restrict__ a,
                    const float* __restrict__ b,
                    float* __restrict__ ws,
                    float* __restrict__ out,
                    int n) {
    __shared__ float4 sb[SLICE_LEN];
    const int slice = blockIdx.y;
    const int base  = slice * SLICE_LEN;

    if (threadIdx.x < SLICE_LEN) {
        const int gj = base + threadIdx.x;
        const float x = b[3 * gj + 0];
        const float y = b[3 * gj + 1];
        const float z = b[3 * gj + 2];
        const float b2 = fmaf(x, x, fmaf(y, y, z * z));
        sb[threadIdx.x] = make_float4(-2.0f * x, -2.0f * y, -2.0f * z, b2);
    }
    if (blockIdx.x == 0 && blockIdx.y == 0 && threadIdx.x == 0)
        out[0] = 0.0f;            // replaces memset node; k2 ordered after k1
    __syncthreads();

    const int a_base = blockIdx.x * (BLOCK * APT);
    v2f ax[HPT], ay[HPT], az[HPT], best[HPT];
    #pragma unroll
    for (int h = 0; h < HPT; ++h) {
        const int i0 = a_base + (2 * h + 0) * BLOCK + threadIdx.x;
        const int i1 = a_base + (2 * h + 1) * BLOCK + threadIdx.x;
        ax[h] = (v2f){a[3 * i0 + 0], a[3 * i1 + 0]};
        ay[h] = (v2f){a[3 * i0 + 1], a[3 * i1 + 1]};
        az[h] = (v2f){a[3 * i0 + 2], a[3 * i1 + 2]};
        best[h] = (v2f){3.4028235e38f, 3.4028235e38f};
    }

    #pragma unroll 4
    for (int j = 0; j < SLICE_LEN; j += 2) {
        const float4 v0 = sb[j];              // wave-uniform broadcast
        const float4 v1 = sb[j + 1];
        #pragma unroll
        for (int h = 0; h < HPT; ++h) {
            v2f t0 = __builtin_elementwise_fma(az[h], (v2f){v0.z, v0.z}, (v2f){v0.w, v0.w});
            t0 = __builtin_elementwise_fma(ay[h], (v2f){v0.y, v0.y}, t0);
            t0 = __builtin_elementwise_fma(ax[h], (v2f){v0.x, v0.x}, t0);
            v2f t1 = __builtin_elementwise_fma(az[h], (v2f){v1.z, v1.z}, (v2f){v1.w, v1.w});
            t1 = __builtin_elementwise_fma(ay[h], (v2f){v1.y, v1.y}, t1);
            t1 = __builtin_elementwise_fma(ax[h], (v2f){v1.x, v1.x}, t1);
            // min(min(t0,t1),best) folds to v_min3_f32 per component
            best[h].x = fminf(fminf(t0.x, t1.x), best[h].x);
            best[h].y = fminf(fminf(t0.y, t1.y), best[h].y);
        }
    }

    float* wrow = ws + (size_t)slice * n;
    #pragma unroll
    for (int h = 0; h < HPT; ++h) {
        wrow[a_base + (2 * h + 0) * BLOCK + threadIdx.x] = best[h].x;
        wrow[a_base + (2 * h + 1) * BLOCK + threadIdx.x] = best[h].y;
    }
}

__global__ __launch_bounds__(BLOCK)
void cd_reduce_kernel(const float* __restrict__ a,
                      const float* __restrict__ ws,
                      float* __restrict__ out,
                      int n) {
    __shared__ float red[BLOCK / 64];
    const int i = blockIdx.x * BLOCK + threadIdx.x;   // one thread per a-point

    float m = 3.4028235e38f;
    #pragma unroll 8
    for (int s = 0; s < SLICES; ++s)
        m = fminf(m, ws[(size_t)s * n + i]);          // coalesced

    const float x = a[3 * i + 0];
    const float y = a[3 * i + 1];
    const float z = a[3 * i + 2];
    const float a2 = fmaf(x, x, fmaf(y, y, z * z));
    float sum = sqrtf(fmaxf(m + a2, 0.0f));

    for (int off = 32; off > 0; off >>= 1)
        sum += __shfl_down(sum, off, 64);

    const int lane = threadIdx.x & 63;
    const int wave = threadIdx.x >> 6;
    if (lane == 0) red[wave] = sum;
    __syncthreads();
    if (threadIdx.x == 0) {
        float t = 0.0f;
        for (int w = 0; w < BLOCK / 64; ++w) t += red[w];
        atomicAdd(out, t);
    }
}

extern "C" void kernel_launch(void* const* d_in, const int* in_sizes, int n_in,
                              void* d_out, int out_size, void* d_ws, size_t ws_size,
                              hipStream_t stream) {
    const float* a = (const float*)d_in[0];
    const float* b = (const float*)d_in[1];
    float* out = (float*)d_out;
    const int n = in_sizes[0] / 3;    // 16384
    float* ws = (float*)d_ws;         // SLICES * n floats = 16 MB

    dim3 grid(ATILES, SLICES);        // 4 x 256 = 1024 blocks, 4 per CU
    cd_pair_kernel<<<grid, BLOCK, 0, stream>>>(a, b, ws, out, n);
    cd_reduce_kernel<<<n / BLOCK, BLOCK, 0, stream>>>(a, ws, out, n);
}

// Round 7
// 87.464 us; speedup vs baseline: 1.0624x; 1.0624x over previous
//
#include <hip/hip_runtime.h>
#include <math.h>

// Chamfer one-sided NN distance sum. N = M = 16384, D = 3, fp32 -> scalar fp32.
//
// k1 pair: grid (ATILES=4, SLICES=128) = 512 blocks. Each thread owns 16
//   a-points as 8 <2 x float>. Inner math forced to v_pk_fma_f32 via inline
//   asm with VOP3P op_sel broadcasts (b-components read lo/hi halves of the
//   64-bit LDS pairs directly — no broadcast movs, no scalarization):
//     t = pk_fma(az, bz.., b2..)   op_sel:[0,0,1] op_sel_hi:[1,0,1]
//     t = pk_fma(ay, by.., t)      op_sel:[0,1,0] op_sel_hi:[1,1,1]
//     t = pk_fma(ax, bx.., t)      op_sel:[0,0,0] op_sel_hi:[1,0,1]
//   then per-component fminf(fminf(t0,t1),best) -> v_min3_f32.
//   = 2.0 VALU slots/pair, guaranteed. LDS: b staged as v2f pairs
//   (-2bx,-2by),(-2bz,|b|^2) -> ds_read_b64 broadcasts, 0 conflicts.
//   Partial mins -> ws[slice][a], no atomics. Block (0,0) zeroes out[0].
// k2 reduce: min over 128 slices, d = sqrt(max(min+|a|^2,0)), wave+block
//   sum, one atomicAdd per block.

#define BLOCK 256
#define HPT   8                   // <2 x float> per thread -> 16 a-points
#define APT   (2 * HPT)
#define SLICES 128
#define SLICE_LEN 128             // 16384 / SLICES
#define ATILES 4                  // 16384 / (BLOCK * APT)

typedef float v2f __attribute__((ext_vector_type(2)));

// t = a * broadcast(lo(zw)) + broadcast(hi(zw))   [z-term + b2 seed]
#define PK_FMA_Z(t, a, zw) \
    asm("v_pk_fma_f32 %0, %1, %2, %2 op_sel:[0,0,1] op_sel_hi:[1,0,1]" \
        : "=v"(t) : "v"(a), "v"(zw))
// t = a * broadcast(hi(xy)) + c                    [y-term]
#define PK_FMA_Y(t, a, xy, c) \
    asm("v_pk_fma_f32 %0, %1, %2, %3 op_sel:[0,1,0] op_sel_hi:[1,1,1]" \
        : "=v"(t) : "v"(a), "v"(xy), "v"(c))
// t = a * broadcast(lo(xy)) + c                    [x-term]
#define PK_FMA_X(t, a, xy, c) \
    asm("v_pk_fma_f32 %0, %1, %2, %3 op_sel:[0,0,0] op_sel_hi:[1,0,1]" \
        : "=v"(t) : "v"(a), "v"(xy), "v"(c))

__global__ __launch_bounds__(BLOCK)
void cd_pair_kernel(const float* __restrict__ a,
                    const float* __restrict__ b,
                    float* __restrict__ ws,
                    float* __restrict__ out,
                    int n) {
    __shared__ v2f sb[2 * SLICE_LEN];   // [2j]=(-2x,-2y), [2j+1]=(-2z,|b|^2)
    const int slice = blockIdx.y;
    const int base  = slice * SLICE_LEN;

    if (threadIdx.x < SLICE_LEN) {
        const int gj = base + threadIdx.x;
        const float x = b[3 * gj + 0];
        const float y = b[3 * gj + 1];
        const float z = b[3 * gj + 2];
        const float b2 = fmaf(x, x, fmaf(y, y, z * z));
        sb[2 * threadIdx.x + 0] = (v2f){-2.0f * x, -2.0f * y};
        sb[2 * threadIdx.x + 1] = (v2f){-2.0f * z, b2};
    }
    if (blockIdx.x == 0 && blockIdx.y == 0 && threadIdx.x == 0)
        out[0] = 0.0f;            // replaces memset node; k2 ordered after k1
    __syncthreads();

    const int a_base = blockIdx.x * (BLOCK * APT);
    v2f ax[HPT], ay[HPT], az[HPT], best[HPT];
    #pragma unroll
    for (int h = 0; h < HPT; ++h) {
        const int i0 = a_base + (2 * h + 0) * BLOCK + threadIdx.x;
        const int i1 = a_base + (2 * h + 1) * BLOCK + threadIdx.x;
        ax[h] = (v2f){a[3 * i0 + 0], a[3 * i1 + 0]};
        ay[h] = (v2f){a[3 * i0 + 1], a[3 * i1 + 1]};
        az[h] = (v2f){a[3 * i0 + 2], a[3 * i1 + 2]};
        best[h] = (v2f){3.4028235e38f, 3.4028235e38f};
    }

    for (int j = 0; j < SLICE_LEN; j += 2) {
        const v2f xy0 = sb[2 * j + 0];        // wave-uniform ds_read_b64
        const v2f zw0 = sb[2 * j + 1];
        const v2f xy1 = sb[2 * j + 2];
        const v2f zw1 = sb[2 * j + 3];
        #pragma unroll
        for (int h = 0; h < HPT; ++h) {
            v2f t0, t1, u0, u1;
            PK_FMA_Z(t0, az[h], zw0);
            PK_FMA_Y(u0, ay[h], xy0, t0);
            PK_FMA_X(t0, ax[h], xy0, u0);
            PK_FMA_Z(t1, az[h], zw1);
            PK_FMA_Y(u1, ay[h], xy1, t1);
            PK_FMA_X(t1, ax[h], xy1, u1);
            // v_min3_f32 per component (sub-register refs, no extract cost)
            best[h].x = fminf(fminf(t0.x, t1.x), best[h].x);
            best[h].y = fminf(fminf(t0.y, t1.y), best[h].y);
        }
    }

    float* wrow = ws + (size_t)slice * n;
    #pragma unroll
    for (int h = 0; h < HPT; ++h) {
        wrow[a_base + (2 * h + 0) * BLOCK + threadIdx.x] = best[h].x;
        wrow[a_base + (2 * h + 1) * BLOCK + threadIdx.x] = best[h].y;
    }
}

__global__ __launch_bounds__(BLOCK)
void cd_reduce_kernel(const float* __restrict__ a,
                      const float* __restrict__ ws,
                      float* __restrict__ out,
                      int n) {
    __shared__ float red[BLOCK / 64];
    const int i = blockIdx.x * BLOCK + threadIdx.x;   // one thread per a-point

    float m = 3.4028235e38f;
    #pragma unroll 4
    for (int s = 0; s < SLICES; ++s)
        m = fminf(m, ws[(size_t)s * n + i]);          // coalesced

    const float x = a[3 * i + 0];
    const float y = a[3 * i + 1];
    const float z = a[3 * i + 2];
    const float a2 = fmaf(x, x, fmaf(y, y, z * z));
    float sum = sqrtf(fmaxf(m + a2, 0.0f));

    for (int off = 32; off > 0; off >>= 1)
        sum += __shfl_down(sum, off, 64);

    const int lane = threadIdx.x & 63;
    const int wave = threadIdx.x >> 6;
    if (lane == 0) red[wave] = sum;
    __syncthreads();
    if (threadIdx.x == 0) {
        float t = 0.0f;
        for (int w = 0; w < BLOCK / 64; ++w) t += red[w];
        atomicAdd(out, t);
    }
}

extern "C" void kernel_launch(void* const* d_in, const int* in_sizes, int n_in,
                              void* d_out, int out_size, void* d_ws, size_t ws_size,
                              hipStream_t stream) {
    const float* a = (const float*)d_in[0];
    const float* b = (const float*)d_in[1];
    float* out = (float*)d_out;
    const int n = in_sizes[0] / 3;    // 16384
    float* ws = (float*)d_ws;         // SLICES * n floats = 8 MB

    dim3 grid(ATILES, SLICES);        // 4 x 128 = 512 blocks
    cd_pair_kernel<<<grid, BLOCK, 0, stream>>>(a, b, ws, out, n);
    cd_reduce_kernel<<<n / BLOCK, BLOCK, 0, stream>>>(a, ws, out, n);
}